// Round 1
// 2830.277 us; speedup vs baseline: 1.1261x; 1.1261x over previous
//
#include <hip/hip_runtime.h>
#include <stdint.h>

#define T_TOK 8192
#define HD    2048
#define NE    32
#define KTOP  8
#define IM    768
#define IS    4096

typedef unsigned short u16;
typedef __attribute__((ext_vector_type(8))) short bf16x8;
typedef __attribute__((ext_vector_type(4))) float f32x4;

__device__ __forceinline__ u16 f2b(float f) {
    union { float f; unsigned u; } c; c.f = f;
    unsigned u = c.u;
    return (u16)((u + 0x7FFFu + ((u >> 16) & 1u)) >> 16);
}

// global -> LDS direct copy, 16B per lane. LDS dest is wave-uniform base +
// lane*16 (m104/m108); global src is per-lane. AS casts go through integers
// (flat->local is low-32 truncation in the AMDGPU backend).
__device__ __forceinline__ void gld16(const void* g, void* l) {
    __builtin_amdgcn_global_load_lds(
        (__attribute__((address_space(1))) void*)(uintptr_t)g,
        (__attribute__((address_space(3))) void*)(uint32_t)(uintptr_t)l,
        16, 0, 0);
}

// ---------------------------------------------------------------------------
// Router: logits (fp32, written to d_out tail), softmax+top8+renorm,
// sigmoid shared gate, fused fp32->bf16 cast of x. One block per token.
// ---------------------------------------------------------------------------
__global__ __launch_bounds__(256) void router_kernel(
    const float* __restrict__ x, const float* __restrict__ gate_w,
    const float* __restrict__ sgw, float* __restrict__ logits_out,
    u16* __restrict__ xb, float* __restrict__ sgvals,
    int* __restrict__ topk_idx, float* __restrict__ topk_w,
    int* __restrict__ counts)
{
    const int t = blockIdx.x, tid = threadIdx.x;
    __shared__ __align__(16) float xrow[HD];
    __shared__ float red[256];
    __shared__ float sh_logit[NE];

    const float4* xr = (const float4*)(x + (size_t)t * HD);
    float4 v0 = xr[tid * 2], v1 = xr[tid * 2 + 1];
    *(float4*)&xrow[tid * 8]     = v0;
    *(float4*)&xrow[tid * 8 + 4] = v1;
    ushort4 p0; p0.x = f2b(v0.x); p0.y = f2b(v0.y); p0.z = f2b(v0.z); p0.w = f2b(v0.w);
    ushort4 p1; p1.x = f2b(v1.x); p1.y = f2b(v1.y); p1.z = f2b(v1.z); p1.w = f2b(v1.w);
    *(ushort4*)&xb[(size_t)t * HD + tid * 8]     = p0;
    *(ushort4*)&xb[(size_t)t * HD + tid * 8 + 4] = p1;
    __syncthreads();

    const int e = tid & 31, seg = tid >> 5;
    float acc = 0.f;
    const float* gwp = gate_w + e;
    for (int j = seg * 256; j < seg * 256 + 256; ++j)
        acc = fmaf(xrow[j], gwp[j * NE], acc);
    red[tid] = acc;
    __syncthreads();
    if (tid < NE) {
        float l = 0.f;
        #pragma unroll
        for (int s = 0; s < 8; ++s) l += red[s * 32 + tid];
        sh_logit[tid] = l;
        logits_out[(size_t)t * NE + tid] = l;
    }
    __syncthreads();

    float sacc = v0.x * sgw[tid * 8 + 0] + v0.y * sgw[tid * 8 + 1] + v0.z * sgw[tid * 8 + 2] + v0.w * sgw[tid * 8 + 3]
               + v1.x * sgw[tid * 8 + 4] + v1.y * sgw[tid * 8 + 5] + v1.z * sgw[tid * 8 + 6] + v1.w * sgw[tid * 8 + 7];
    red[tid] = sacc;
    __syncthreads();
    if (tid < 128) red[tid] += red[tid + 128];
    __syncthreads();
    if (tid < 64) {
        float s2 = red[tid] + red[tid + 64];
        #pragma unroll
        for (int off = 32; off; off >>= 1) s2 += __shfl_xor(s2, off, 64);
        if (tid == 0) sgvals[t] = 1.f / (1.f + __expf(-s2));

        float v = (tid < NE) ? sh_logit[tid] : -3.0e38f;
        float m = v;
        #pragma unroll
        for (int off = 32; off; off >>= 1) m = fmaxf(m, __shfl_xor(m, off, 64));
        float p = __expf(v - m);
        if (tid >= NE) p = 0.f;
        float ssum = p;
        #pragma unroll
        for (int off = 32; off; off >>= 1) ssum += __shfl_xor(ssum, off, 64);
        float myp = p / ssum;

        float selv[KTOP]; int seli[KTOP];
        float sumtop = 0.f;
        #pragma unroll
        for (int k = 0; k < KTOP; ++k) {
            float bv = myp; int bi = tid;
            #pragma unroll
            for (int off = 32; off; off >>= 1) {
                float ov = __shfl_xor(bv, off, 64);
                int   oi = __shfl_xor(bi, off, 64);
                if (ov > bv || (ov == bv && oi < bi)) { bv = ov; bi = oi; }
            }
            selv[k] = bv; seli[k] = bi; sumtop += bv;
            if (tid == bi) myp = -1.f;
        }
        if (tid == 0) {
            #pragma unroll
            for (int k = 0; k < KTOP; ++k) {
                topk_idx[(size_t)t * KTOP + k] = seli[k];
                topk_w[(size_t)t * KTOP + k]   = selv[k] / sumtop;
                atomicAdd(&counts[seli[k]], 1);
            }
        }
    }
}

__global__ void offsets_kernel(const int* __restrict__ counts,
                               int* __restrict__ offsets, int* __restrict__ cursor)
{
    if (threadIdx.x == 0) {
        int a = 0;
        for (int e = 0; e < NE; ++e) { offsets[e] = a; cursor[e] = a; a += counts[e]; }
    }
}

__global__ __launch_bounds__(256) void scatter_kernel(
    const int* __restrict__ topk_idx, const float* __restrict__ topk_w,
    int* __restrict__ cursor, int* __restrict__ token_list, float* __restrict__ weight_list)
{
    int i = blockIdx.x * 256 + threadIdx.x;
    int e = topk_idx[i];
    int pos = atomicAdd(&cursor[e], 1);
    token_list[pos]  = i >> 3;
    weight_list[pos] = topk_w[i];
}

// ---------------------------------------------------------------------------
// Weight converter: fp32 [K][N] -> bf16 MFMA panels. One block = one panel
// (k-tile 32 x n-block 128) laid out as the exact LDS image the GEMM stages:
// [k-chunk(4)][n-row(128)][8 u16], 8 KB contiguous. Panel order per expert:
// n-block-major, then k-tile (so a block's K-loop streams consecutive panels).
// ---------------------------------------------------------------------------
__global__ __launch_bounds__(256) void convert_k(
    const float* __restrict__ W, u16* __restrict__ P, int K, int N)
{
    const int n0 = blockIdx.x * 128, kt = blockIdx.y * 32;
    const size_t eoff = (size_t)blockIdx.z * K * N;
    const int tid = threadIdx.x;
    __shared__ __align__(16) float tile[32][128];

    const float* Wb = W + eoff + (size_t)kt * N + n0;
    #pragma unroll
    for (int p = 0; p < 4; ++p) {
        int k = p * 8 + (tid >> 5);
        *(float4*)&tile[k][(tid & 31) * 4] = *(const float4*)(Wb + (size_t)k * N + (tid & 31) * 4);
    }
    __syncthreads();

    const int kblk = K >> 5;
    u16* Pp = P + eoff + ((size_t)blockIdx.x * kblk + blockIdx.y) * 4096;
    #pragma unroll
    for (int s = 0; s < 2; ++s) {
        int i = s * 256 + tid;          // chunk 0..511
        int c = i >> 7, n = i & 127;
        union { u16 us[8]; uint4 v; } pk;
        #pragma unroll
        for (int q = 0; q < 8; ++q) pk.us[q] = f2b(tile[c * 8 + q][n]);
        *(uint4*)&Pp[(size_t)i * 8] = pk.v;
    }
}

// ---------------------------------------------------------------------------
// Fast 128x128 bf16-MFMA GEMM (m97-style): A bf16 row-major, B pre-converted
// panels. Staging = global_load_lds_dwordx4 only; LDS tiles stored
// [chunk][row][16B] so every fragment ds_read_b128 is lane-consecutive
// (conflict-free); double-buffered, one __syncthreads per K-step.
// MODE 0: shared gate+up   MODE 1: shared down (store fp32)
// MODE 2: expert gate+up   MODE 3: expert down (atomic scatter-add)
// ---------------------------------------------------------------------------
template<int MODE>
__global__ __launch_bounds__(256, 2) void gemm_f(
    const u16* __restrict__ Asrc, const u16* __restrict__ B0p,
    const u16* __restrict__ B1p, u16* __restrict__ outb,
    float* __restrict__ outf, const float* __restrict__ scale,
    const int* __restrict__ token_list, const int* __restrict__ counts,
    const int* __restrict__ offsets)
{
    constexpr bool DUAL   = (MODE == 0 || MODE == 2);
    constexpr bool EXPERT = (MODE >= 2);
    constexpr int KTOT = (MODE == 0 || MODE == 2) ? HD : (MODE == 1 ? IS : IM);
    constexpr int NTOT = (MODE == 0) ? IS : (MODE == 2 ? IM : HD);
    constexpr int NTIL = DUAL ? 3 : 2;
    constexpr int NKT  = KTOT / 32;

    const int tid = threadIdx.x;
    const int ex  = blockIdx.z;
    const int n_e = EXPERT ? counts[ex]  : T_TOK;
    const int off = EXPERT ? offsets[ex] : 0;
    const int m0  = blockIdx.y * 128;
    if (m0 >= n_e) return;
    const int n0 = blockIdx.x * 128;

    const size_t ewoff = EXPERT ? (size_t)ex * KTOT * NTOT : 0;

    // [buf(2)][tile(NTIL)][4096 u16]; tile image = [chunk(4)][row(128)][8 u16]
    __shared__ __align__(16) u16 sh[2 * NTIL * 4096];

    const int w = tid >> 6, lane = tid & 63;
    const int lr = lane & 15, quad = lane >> 4;
    const int wm = (w >> 1) * 64, wn = (w & 1) * 64;
    const int ldsw = w * 512;            // wave-uniform dest: 64 lanes * 8 u16

    // per-thread A source for the two 4KB staging sweeps
    const u16* asrc[2];
    #pragma unroll
    for (int s = 0; s < 2; ++s) {
        int i = s * 256 + tid;
        int c = i >> 7, r = i & 127;
        int grow = m0 + r;
        int gc = grow < n_e ? grow : n_e - 1;
        size_t rowidx;
        if (MODE == 0 || MODE == 1) rowidx = (size_t)grow;
        else if (MODE == 2) rowidx = (size_t)token_list[off + gc];
        else rowidx = (size_t)(off + gc);
        asrc[s] = Asrc + rowidx * KTOT + c * 8;
    }
    const u16* b0 = B0p + ewoff + ((size_t)(n0 >> 7) * NKT) * 4096 + (size_t)tid * 8;
    const u16* b1 = nullptr;
    if constexpr (DUAL) b1 = B1p + ewoff + ((size_t)(n0 >> 7) * NKT) * 4096 + (size_t)tid * 8;

    auto stage = [&](int buf, int kt) {
        u16* A  = sh + (size_t)(buf * NTIL + 0) * 4096;
        u16* Bt = sh + (size_t)(buf * NTIL + 1) * 4096;
        #pragma unroll
        for (int s = 0; s < 2; ++s) {
            gld16(asrc[s] + kt, A + s * 2048 + ldsw);
            gld16(b0 + (size_t)(kt >> 5) * 4096 + s * 2048, Bt + s * 2048 + ldsw);
        }
        if constexpr (DUAL) {
            u16* Bu = sh + (size_t)(buf * NTIL + 2) * 4096;
            #pragma unroll
            for (int s = 0; s < 2; ++s)
                gld16(b1 + (size_t)(kt >> 5) * 4096 + s * 2048, Bu + s * 2048 + ldsw);
        }
    };

    f32x4 acc0[4][4], acc1[4][4];
    #pragma unroll
    for (int a = 0; a < 4; ++a)
        #pragma unroll
        for (int b = 0; b < 4; ++b)
            #pragma unroll
            for (int q = 0; q < 4; ++q) { acc0[a][b][q] = 0.f; if constexpr (DUAL) acc1[a][b][q] = 0.f; }

    stage(0, 0);
    int cur = 0;
    for (int kt = 0; kt < KTOT; kt += 32) {
        __syncthreads();                      // vmcnt(0) drained by compiler
        if (kt + 32 < KTOT) stage(cur ^ 1, kt + 32);   // overlap with compute

        const u16* A  = sh + (size_t)(cur * NTIL + 0) * 4096;
        const u16* B0 = sh + (size_t)(cur * NTIL + 1) * 4096;

        bf16x8 af[4], bf0[4], bf1[4];
        #pragma unroll
        for (int mt = 0; mt < 4; ++mt)
            af[mt]  = *(const bf16x8*)&A [quad * 1024 + (wm + mt * 16 + lr) * 8];
        #pragma unroll
        for (int nt = 0; nt < 4; ++nt)
            bf0[nt] = *(const bf16x8*)&B0[quad * 1024 + (wn + nt * 16 + lr) * 8];
        if constexpr (DUAL) {
            const u16* B1 = sh + (size_t)(cur * NTIL + 2) * 4096;
            #pragma unroll
            for (int nt = 0; nt < 4; ++nt)
                bf1[nt] = *(const bf16x8*)&B1[quad * 1024 + (wn + nt * 16 + lr) * 8];
        }
        #pragma unroll
        for (int mt = 0; mt < 4; ++mt)
            #pragma unroll
            for (int nt = 0; nt < 4; ++nt) {
                acc0[mt][nt] = __builtin_amdgcn_mfma_f32_16x16x32_bf16(af[mt], bf0[nt], acc0[mt][nt], 0, 0, 0);
                if constexpr (DUAL)
                    acc1[mt][nt] = __builtin_amdgcn_mfma_f32_16x16x32_bf16(af[mt], bf1[nt], acc1[mt][nt], 0, 0, 0);
            }
        cur ^= 1;
    }

    // Epilogue. C/D layout: col = lane&15, row = quad*4 + reg (m89/m91-verified)
    if (MODE == 0 || MODE == 2) {
        #pragma unroll
        for (int mt = 0; mt < 4; ++mt)
            #pragma unroll
            for (int rg = 0; rg < 4; ++rg) {
                const int grow = m0 + wm + mt * 16 + quad * 4 + rg;
                if (!EXPERT || grow < n_e) {
                    u16* orow = outb + (size_t)(EXPERT ? (off + grow) : grow) * NTOT + n0 + wn + lr;
                    #pragma unroll
                    for (int nt = 0; nt < 4; ++nt) {
                        float g = acc0[mt][nt][rg];
                        float u = acc1[mt][nt][rg];
                        float sgm = 1.f / (1.f + __expf(-g));
                        orow[nt * 16] = f2b(g * sgm * u);
                    }
                }
            }
    } else if (MODE == 1) {
        #pragma unroll
        for (int mt = 0; mt < 4; ++mt)
            #pragma unroll
            for (int rg = 0; rg < 4; ++rg) {
                const int grow = m0 + wm + mt * 16 + quad * 4 + rg;
                const float s = scale[grow];
                float* orow = outf + (size_t)grow * HD + n0 + wn + lr;
                #pragma unroll
                for (int nt = 0; nt < 4; ++nt) orow[nt * 16] = s * acc0[mt][nt][rg];
            }
    } else {
        #pragma unroll
        for (int mt = 0; mt < 4; ++mt)
            #pragma unroll
            for (int rg = 0; rg < 4; ++rg) {
                const int grow = m0 + wm + mt * 16 + quad * 4 + rg;
                if (grow < n_e) {
                    const int tok   = token_list[off + grow];
                    const float wgt = scale[off + grow];
                    float* orow = outf + (size_t)tok * HD + n0 + wn + lr;
                    #pragma unroll
                    for (int nt = 0; nt < 4; ++nt)
                        unsafeAtomicAdd(&orow[nt * 16], wgt * acc0[mt][nt][rg]);
                }
            }
    }
}

// ---------------------------------------------------------------------------
// Legacy GEMM (verbatim previous version) — fallback when ws_size is too
// small for the bf16 weight panels.
// ---------------------------------------------------------------------------
template<int MODE>
__global__ __launch_bounds__(256, 2) void gemm_l(
    const u16* __restrict__ Asrc, const float* __restrict__ B0g,
    const float* __restrict__ B1g, u16* __restrict__ outb,
    float* __restrict__ outf, const float* __restrict__ scale,
    const int* __restrict__ token_list, const int* __restrict__ counts,
    const int* __restrict__ offsets)
{
    constexpr bool DUAL   = (MODE == 0 || MODE == 2);
    constexpr bool EXPERT = (MODE >= 2);
    constexpr int KTOT = (MODE == 0 || MODE == 2) ? HD : (MODE == 1 ? IS : IM);
    constexpr int NTOT = (MODE == 0) ? IS : (MODE == 2 ? IM : HD);
    constexpr int LDA  = (MODE == 0 || MODE == 2) ? HD : (MODE == 1 ? IS : IM);

    const int tid = threadIdx.x;
    const int ex  = blockIdx.z;
    const int n_e = EXPERT ? counts[ex]  : T_TOK;
    const int off = EXPERT ? offsets[ex] : 0;
    const int m0  = blockIdx.y * 128;
    if (m0 >= n_e) return;
    const int n0 = blockIdx.x * 128;

    const float* B0 = B0g + (EXPERT ? (size_t)ex * KTOT * NTOT : 0);
    const float* B1 = DUAL ? (B1g + (EXPERT ? (size_t)ex * KTOT * NTOT : 0)) : nullptr;

    __shared__ __align__(16) u16 As [128 * 40];
    __shared__ __align__(16) u16 Bs0[128 * 40];
    __shared__ __align__(16) u16 Bs1[DUAL ? 128 * 40 : 8];

    const u16* aptr[2]; int aoff[2];
    #pragma unroll
    for (int i = 0; i < 2; ++i) {
        int c = tid + i * 256;
        int r = c >> 2, xo = c & 3;
        int grow = m0 + r;
        size_t rowidx;
        if (MODE == 0 || MODE == 1) rowidx = (size_t)grow;
        else if (MODE == 2) rowidx = (size_t)((grow < n_e) ? token_list[off + grow] : 0);
        else rowidx = (size_t)(off + grow);
        aptr[i] = Asrc + rowidx * LDA + xo * 8;
        aoff[i] = r * 40 + xo * 8;
    }

    const int kb = tid >> 5, nb = tid & 31;
    const float* bp0 = B0 + (size_t)(kb * 4) * NTOT + n0 + nb * 4;
    const float* bp1 = DUAL ? (B1 + (size_t)(kb * 4) * NTOT + n0 + nb * 4) : nullptr;
    const int bo = (nb * 4) * 40 + kb * 4;

    const int lane = tid & 63, wv = tid >> 6;
    const int wm = (wv >> 1) * 64, wn = (wv & 1) * 64;
    const int lr = lane & 15, quad = lane >> 4;

    f32x4 acc0[4][4], acc1[4][4];
    #pragma unroll
    for (int a = 0; a < 4; ++a)
        #pragma unroll
        for (int b = 0; b < 4; ++b)
            #pragma unroll
            for (int q = 0; q < 4; ++q) { acc0[a][b][q] = 0.f; if (DUAL) acc1[a][b][q] = 0.f; }

    for (int kt = 0; kt < KTOT; kt += 32) {
        uint4 av0 = *(const uint4*)(aptr[0] + kt);
        uint4 av1 = *(const uint4*)(aptr[1] + kt);
        float4 b0v[4], b1v[4];
        #pragma unroll
        for (int i = 0; i < 4; ++i) b0v[i] = *(const float4*)(bp0 + (size_t)(kt + i) * NTOT);
        if (DUAL) {
            #pragma unroll
            for (int i = 0; i < 4; ++i) b1v[i] = *(const float4*)(bp1 + (size_t)(kt + i) * NTOT);
        }
        __syncthreads();
        *(uint4*)&As[aoff[0]] = av0;
        *(uint4*)&As[aoff[1]] = av1;
        {
            const float* f0 = (const float*)b0v;
            #pragma unroll
            for (int j = 0; j < 4; ++j) {
                ushort4 tw; tw.x = f2b(f0[0 * 4 + j]); tw.y = f2b(f0[1 * 4 + j]);
                            tw.z = f2b(f0[2 * 4 + j]); tw.w = f2b(f0[3 * 4 + j]);
                *(ushort4*)&Bs0[bo + j * 40] = tw;
            }
        }
        if (DUAL) {
            const float* f1 = (const float*)b1v;
            #pragma unroll
            for (int j = 0; j < 4; ++j) {
                ushort4 tw; tw.x = f2b(f1[0 * 4 + j]); tw.y = f2b(f1[1 * 4 + j]);
                            tw.z = f2b(f1[2 * 4 + j]); tw.w = f2b(f1[3 * 4 + j]);
                *(ushort4*)&Bs1[bo + j * 40] = tw;
            }
        }
        __syncthreads();

        bf16x8 af[4], bf0[4], bf1[4];
        #pragma unroll
        for (int mt = 0; mt < 4; ++mt) af[mt]  = *(const bf16x8*)&As [(wm + mt * 16 + lr) * 40 + quad * 8];
        #pragma unroll
        for (int nt = 0; nt < 4; ++nt) bf0[nt] = *(const bf16x8*)&Bs0[(wn + nt * 16 + lr) * 40 + quad * 8];
        if (DUAL) {
            #pragma unroll
            for (int nt = 0; nt < 4; ++nt) bf1[nt] = *(const bf16x8*)&Bs1[(wn + nt * 16 + lr) * 40 + quad * 8];
        }
        #pragma unroll
        for (int mt = 0; mt < 4; ++mt)
            #pragma unroll
            for (int nt = 0; nt < 4; ++nt) {
                acc0[mt][nt] = __builtin_amdgcn_mfma_f32_16x16x32_bf16(af[mt], bf0[nt], acc0[mt][nt], 0, 0, 0);
                if (DUAL)
                    acc1[mt][nt] = __builtin_amdgcn_mfma_f32_16x16x32_bf16(af[mt], bf1[nt], acc1[mt][nt], 0, 0, 0);
            }
    }

    if (MODE == 0 || MODE == 2) {
        #pragma unroll
        for (int mt = 0; mt < 4; ++mt)
            #pragma unroll
            for (int rg = 0; rg < 4; ++rg) {
                const int grow = m0 + wm + mt * 16 + quad * 4 + rg;
                if (!EXPERT || grow < n_e) {
                    u16* orow = outb + (size_t)(EXPERT ? (off + grow) : grow) * NTOT + n0 + wn + lr;
                    #pragma unroll
                    for (int nt = 0; nt < 4; ++nt) {
                        float g = acc0[mt][nt][rg];
                        float u = acc1[mt][nt][rg];
                        float sgm = 1.f / (1.f + __expf(-g));
                        orow[nt * 16] = f2b(g * sgm * u);
                    }
                }
            }
    } else if (MODE == 1) {
        #pragma unroll
        for (int mt = 0; mt < 4; ++mt)
            #pragma unroll
            for (int rg = 0; rg < 4; ++rg) {
                const int grow = m0 + wm + mt * 16 + quad * 4 + rg;
                const float s = scale[grow];
                float* orow = outf + (size_t)grow * HD + n0 + wn + lr;
                #pragma unroll
                for (int nt = 0; nt < 4; ++nt) orow[nt * 16] = s * acc0[mt][nt][rg];
            }
    } else {
        #pragma unroll
        for (int mt = 0; mt < 4; ++mt)
            #pragma unroll
            for (int rg = 0; rg < 4; ++rg) {
                const int grow = m0 + wm + mt * 16 + quad * 4 + rg;
                if (grow < n_e) {
                    const int tok   = token_list[off + grow];
                    const float wgt = scale[off + grow];
                    float* orow = outf + (size_t)tok * HD + n0 + wn + lr;
                    #pragma unroll
                    for (int nt = 0; nt < 4; ++nt)
                        unsafeAtomicAdd(&orow[nt * 16], wgt * acc0[mt][nt][rg]);
                }
            }
    }
}

// ---------------------------------------------------------------------------
// workspace layout (bytes)
// ---------------------------------------------------------------------------
#define OFF_XB      ((size_t)0)            // T*H bf16            = 33554432
#define OFF_HSH     ((size_t)33554432)     // T*IS bf16           = 67108864
#define OFF_HMID    ((size_t)100663296)    // T*K*IM bf16         = 100663296
#define OFF_SG      ((size_t)201326592)    // T fp32
#define OFF_TOPKI   ((size_t)201359360)
#define OFF_TOPKW   ((size_t)201621504)
#define OFF_TOKL    ((size_t)201883648)
#define OFF_WGTL    ((size_t)202145792)
#define OFF_COUNTS  ((size_t)202407936)
#define OFF_CURSOR  ((size_t)202408064)
#define OFF_OFFSETS ((size_t)202408192)
// bf16 weight panels (fast path only)
#define OFF_PWG     ((size_t)202408448)    // 32*2048*768*2  = 100663296
#define OFF_PWU     ((size_t)303071744)
#define OFF_PWD     ((size_t)403735040)
#define OFF_PSG     ((size_t)504398336)    // 2048*4096*2    = 16777216
#define OFF_PSU     ((size_t)521175552)
#define OFF_PSD     ((size_t)537952768)
#define WS_NEED     ((size_t)554729984)

extern "C" void kernel_launch(void* const* d_in, const int* in_sizes, int n_in,
                              void* d_out, int out_size, void* d_ws, size_t ws_size,
                              hipStream_t stream)
{
    const float* x   = (const float*)d_in[0];
    const float* gw  = (const float*)d_in[1];
    const float* Wg  = (const float*)d_in[2];
    const float* Wu  = (const float*)d_in[3];
    const float* Wd  = (const float*)d_in[4];
    const float* Sg  = (const float*)d_in[5];
    const float* Su  = (const float*)d_in[6];
    const float* Sd  = (const float*)d_in[7];
    const float* sgw = (const float*)d_in[8];

    float* out        = (float*)d_out;
    float* logits_out = out + (size_t)T_TOK * HD;

    char* ws = (char*)d_ws;
    u16*   xb      = (u16*)  (ws + OFF_XB);
    u16*   hshared = (u16*)  (ws + OFF_HSH);
    u16*   hmid    = (u16*)  (ws + OFF_HMID);
    float* sgvals  = (float*)(ws + OFF_SG);
    int*   topk_i  = (int*)  (ws + OFF_TOPKI);
    float* topk_wv = (float*)(ws + OFF_TOPKW);
    int*   tok_lst = (int*)  (ws + OFF_TOKL);
    float* wgt_lst = (float*)(ws + OFF_WGTL);
    int*   counts  = (int*)  (ws + OFF_COUNTS);
    int*   cursor  = (int*)  (ws + OFF_CURSOR);
    int*   offsets = (int*)  (ws + OFF_OFFSETS);

    hipMemsetAsync(counts, 0, 256, stream);  // counts + cursor

    router_kernel<<<T_TOK, 256, 0, stream>>>(x, gw, sgw, logits_out, xb, sgvals,
                                             topk_i, topk_wv, counts);
    offsets_kernel<<<1, 64, 0, stream>>>(counts, offsets, cursor);
    scatter_kernel<<<T_TOK * KTOP / 256, 256, 0, stream>>>(topk_i, topk_wv, cursor,
                                                           tok_lst, wgt_lst);

    if (ws_size >= WS_NEED) {
        u16* pWg = (u16*)(ws + OFF_PWG);
        u16* pWu = (u16*)(ws + OFF_PWU);
        u16* pWd = (u16*)(ws + OFF_PWD);
        u16* pSg = (u16*)(ws + OFF_PSG);
        u16* pSu = (u16*)(ws + OFF_PSU);
        u16* pSd = (u16*)(ws + OFF_PSD);

        convert_k<<<dim3(IM / 128, HD / 32, NE), 256, 0, stream>>>(Wg, pWg, HD, IM);
        convert_k<<<dim3(IM / 128, HD / 32, NE), 256, 0, stream>>>(Wu, pWu, HD, IM);
        convert_k<<<dim3(HD / 128, IM / 32, NE), 256, 0, stream>>>(Wd, pWd, IM, HD);
        convert_k<<<dim3(IS / 128, HD / 32, 1),  256, 0, stream>>>(Sg, pSg, HD, IS);
        convert_k<<<dim3(IS / 128, HD / 32, 1),  256, 0, stream>>>(Su, pSu, HD, IS);
        convert_k<<<dim3(HD / 128, IS / 32, 1),  256, 0, stream>>>(Sd, pSd, IS, HD);

        gemm_f<0><<<dim3(IS / 128, T_TOK / 128, 1), 256, 0, stream>>>(
            xb, pSg, pSu, hshared, nullptr, nullptr, nullptr, nullptr, nullptr);
        gemm_f<2><<<dim3(IM / 128, T_TOK / 128, NE), 256, 0, stream>>>(
            xb, pWg, pWu, hmid, nullptr, nullptr, tok_lst, counts, offsets);
        gemm_f<1><<<dim3(HD / 128, T_TOK / 128, 1), 256, 0, stream>>>(
            hshared, pSd, nullptr, nullptr, out, sgvals, nullptr, nullptr, nullptr);
        gemm_f<3><<<dim3(HD / 128, T_TOK / 128, NE), 256, 0, stream>>>(
            hmid, pWd, nullptr, nullptr, out, wgt_lst, tok_lst, counts, offsets);
    } else {
        gemm_l<0><<<dim3(IS / 128, T_TOK / 128, 1), 256, 0, stream>>>(
            xb, Sg, Su, hshared, nullptr, nullptr, nullptr, nullptr, nullptr);
        gemm_l<2><<<dim3(IM / 128, T_TOK / 128, NE), 256, 0, stream>>>(
            xb, Wg, Wu, hmid, nullptr, nullptr, tok_lst, counts, offsets);
        gemm_l<1><<<dim3(HD / 128, T_TOK / 128, 1), 256, 0, stream>>>(
            hshared, Sd, nullptr, nullptr, out, sgvals, nullptr, nullptr, nullptr);
        gemm_l<3><<<dim3(HD / 128, T_TOK / 128, NE), 256, 0, stream>>>(
            hmid, Wd, nullptr, nullptr, out, wgt_lst, tok_lst, counts, offsets);
    }
}

// Round 3
// 2807.747 us; speedup vs baseline: 1.1351x; 1.0080x over previous
//
#include <hip/hip_runtime.h>
#include <stdint.h>

#define T_TOK 8192
#define HD    2048
#define NE    32
#define KTOP  8
#define IM    768
#define IS    4096

typedef unsigned short u16;
typedef __attribute__((ext_vector_type(8))) short bf16x8;
typedef __attribute__((ext_vector_type(4))) float f32x4;

__device__ __forceinline__ u16 f2b(float f) {
    union { float f; unsigned u; } c; c.f = f;
    unsigned u = c.u;
    return (u16)((u + 0x7FFFu + ((u >> 16) & 1u)) >> 16);
}

// global -> LDS direct copy, 16B per lane. LDS dest is wave-uniform base +
// lane*16 (m104/m108); global src is per-lane.
__device__ __forceinline__ void gld16(const void* g, void* l) {
    __builtin_amdgcn_global_load_lds(
        (__attribute__((address_space(1))) void*)(uintptr_t)g,
        (__attribute__((address_space(3))) void*)(uint32_t)(uintptr_t)l,
        16, 0, 0);
}

// bijective XCD-chunk swizzle (valid when nwg % 8 == 0; all our grids are)
__device__ __forceinline__ void xcd_swizzle(int& bx, int& by, int& bz) {
    const int gx = gridDim.x, gy = gridDim.y, gz = gridDim.z;
    const int nwg = gx * gy * gz;
    int f = blockIdx.x + gx * (blockIdx.y + gy * blockIdx.z);
    if ((nwg & 7) == 0) f = (f & 7) * (nwg >> 3) + (f >> 3);
    bx = f % gx; f /= gx; by = f % gy; bz = f / gy;
}

// ---------------------------------------------------------------------------
// Router: logits (fp32, written to d_out tail), softmax+top8+renorm,
// sigmoid shared gate, fused fp32->bf16 cast of x. One block per token.
// ---------------------------------------------------------------------------
__global__ __launch_bounds__(256) void router_kernel(
    const float* __restrict__ x, const float* __restrict__ gate_w,
    const float* __restrict__ sgw, float* __restrict__ logits_out,
    u16* __restrict__ xb, float* __restrict__ sgvals,
    int* __restrict__ topk_idx, float* __restrict__ topk_w,
    int* __restrict__ counts)
{
    const int t = blockIdx.x, tid = threadIdx.x;
    __shared__ __align__(16) float xrow[HD];
    __shared__ float red[256];
    __shared__ float sh_logit[NE];

    const float4* xr = (const float4*)(x + (size_t)t * HD);
    float4 v0 = xr[tid * 2], v1 = xr[tid * 2 + 1];
    *(float4*)&xrow[tid * 8]     = v0;
    *(float4*)&xrow[tid * 8 + 4] = v1;
    ushort4 p0; p0.x = f2b(v0.x); p0.y = f2b(v0.y); p0.z = f2b(v0.z); p0.w = f2b(v0.w);
    ushort4 p1; p1.x = f2b(v1.x); p1.y = f2b(v1.y); p1.z = f2b(v1.z); p1.w = f2b(v1.w);
    *(ushort4*)&xb[(size_t)t * HD + tid * 8]     = p0;
    *(ushort4*)&xb[(size_t)t * HD + tid * 8 + 4] = p1;
    __syncthreads();

    const int e = tid & 31, seg = tid >> 5;
    float acc = 0.f;
    const float* gwp = gate_w + e;
    for (int j = seg * 256; j < seg * 256 + 256; ++j)
        acc = fmaf(xrow[j], gwp[j * NE], acc);
    red[tid] = acc;
    __syncthreads();
    if (tid < NE) {
        float l = 0.f;
        #pragma unroll
        for (int s = 0; s < 8; ++s) l += red[s * 32 + tid];
        sh_logit[tid] = l;
        logits_out[(size_t)t * NE + tid] = l;
    }
    __syncthreads();

    float sacc = v0.x * sgw[tid * 8 + 0] + v0.y * sgw[tid * 8 + 1] + v0.z * sgw[tid * 8 + 2] + v0.w * sgw[tid * 8 + 3]
               + v1.x * sgw[tid * 8 + 4] + v1.y * sgw[tid * 8 + 5] + v1.z * sgw[tid * 8 + 6] + v1.w * sgw[tid * 8 + 7];
    red[tid] = sacc;
    __syncthreads();
    if (tid < 128) red[tid] += red[tid + 128];
    __syncthreads();
    if (tid < 64) {
        float s2 = red[tid] + red[tid + 64];
        #pragma unroll
        for (int off = 32; off; off >>= 1) s2 += __shfl_xor(s2, off, 64);
        if (tid == 0) sgvals[t] = 1.f / (1.f + __expf(-s2));

        float v = (tid < NE) ? sh_logit[tid] : -3.0e38f;
        float m = v;
        #pragma unroll
        for (int off = 32; off; off >>= 1) m = fmaxf(m, __shfl_xor(m, off, 64));
        float p = __expf(v - m);
        if (tid >= NE) p = 0.f;
        float ssum = p;
        #pragma unroll
        for (int off = 32; off; off >>= 1) ssum += __shfl_xor(ssum, off, 64);
        float myp = p / ssum;

        float selv[KTOP]; int seli[KTOP];
        float sumtop = 0.f;
        #pragma unroll
        for (int k = 0; k < KTOP; ++k) {
            float bv = myp; int bi = tid;
            #pragma unroll
            for (int off = 32; off; off >>= 1) {
                float ov = __shfl_xor(bv, off, 64);
                int   oi = __shfl_xor(bi, off, 64);
                if (ov > bv || (ov == bv && oi < bi)) { bv = ov; bi = oi; }
            }
            selv[k] = bv; seli[k] = bi; sumtop += bv;
            if (tid == bi) myp = -1.f;
        }
        if (tid == 0) {
            #pragma unroll
            for (int k = 0; k < KTOP; ++k) {
                topk_idx[(size_t)t * KTOP + k] = seli[k];
                topk_w[(size_t)t * KTOP + k]   = selv[k] / sumtop;
                atomicAdd(&counts[seli[k]], 1);
            }
        }
    }
}

__global__ void offsets_kernel(const int* __restrict__ counts,
                               int* __restrict__ offsets, int* __restrict__ cursor)
{
    if (threadIdx.x == 0) {
        int a = 0;
        for (int e = 0; e < NE; ++e) { offsets[e] = a; cursor[e] = a; a += counts[e]; }
    }
}

__global__ __launch_bounds__(256) void scatter_kernel(
    const int* __restrict__ topk_idx, const float* __restrict__ topk_w,
    int* __restrict__ cursor, int* __restrict__ token_list, float* __restrict__ weight_list)
{
    int i = blockIdx.x * 256 + threadIdx.x;
    int e = topk_idx[i];
    int pos = atomicAdd(&cursor[e], 1);
    token_list[pos]  = i >> 3;
    weight_list[pos] = topk_w[i];
}

// ---------------------------------------------------------------------------
// Weight converter: fp32 [K][N] -> bf16 MFMA panels. One block = one panel
// (k-tile 32 x n-block 128) laid out as the exact LDS image the GEMM stages:
// [k-chunk(4)][n-row(128)][8 u16], 8 KB contiguous. Panel order per expert:
// n-block-major, then k-tile.
// ---------------------------------------------------------------------------
__global__ __launch_bounds__(256) void convert_k(
    const float* __restrict__ W, u16* __restrict__ P, int K, int N)
{
    const int n0 = blockIdx.x * 128, kt = blockIdx.y * 32;
    const size_t eoff = (size_t)blockIdx.z * K * N;
    const int tid = threadIdx.x;
    __shared__ __align__(16) float tile[32][128];

    const float* Wb = W + eoff + (size_t)kt * N + n0;
    #pragma unroll
    for (int p = 0; p < 4; ++p) {
        int k = p * 8 + (tid >> 5);
        *(float4*)&tile[k][(tid & 31) * 4] = *(const float4*)(Wb + (size_t)k * N + (tid & 31) * 4);
    }
    __syncthreads();

    const int kblk = K >> 5;
    u16* Pp = P + eoff + ((size_t)blockIdx.x * kblk + blockIdx.y) * 4096;
    #pragma unroll
    for (int s = 0; s < 2; ++s) {
        int i = s * 256 + tid;
        int c = i >> 7, n = i & 127;
        union { u16 us[8]; uint4 v; } pk;
        #pragma unroll
        for (int q = 0; q < 8; ++q) pk.us[q] = f2b(tile[c * 8 + q][n]);
        *(uint4*)&Pp[(size_t)i * 8] = pk.v;
    }
}

// ---------------------------------------------------------------------------
// Fast 128x128 bf16-MFMA GEMM, counted-vmcnt pipeline (T3min+T4+T5+T1):
// triple-buffered LDS, stage issued 2 tiles ahead, ONE raw s_barrier per
// K-step with s_waitcnt vmcnt(N) (N = loads of one tile-set) so prefetch
// loads stay in flight across the barrier. TAIL: when no stage was issued
// this iteration the counted wait would pass vacuously, so the barrier
// before the LAST tile drains with vmcnt(0); the final iteration needs no
// barrier at all (epilogue is register-only).
// MODE 0: shared gate+up   MODE 1: shared down (store fp32)
// MODE 2: expert gate+up   MODE 3: expert down (atomic scatter-add)
// ---------------------------------------------------------------------------
template<int MODE>
__global__ __launch_bounds__(256, (MODE == 0 || MODE == 2) ? 2 : 3) void gemm_f(
    const u16* __restrict__ Asrc, const u16* __restrict__ B0p,
    const u16* __restrict__ B1p, u16* __restrict__ outb,
    float* __restrict__ outf, const float* __restrict__ scale,
    const int* __restrict__ token_list, const int* __restrict__ counts,
    const int* __restrict__ offsets)
{
    constexpr bool DUAL   = (MODE == 0 || MODE == 2);
    constexpr bool EXPERT = (MODE >= 2);
    constexpr int KTOT = (MODE == 0 || MODE == 2) ? HD : (MODE == 1 ? IS : IM);
    constexpr int NTOT = (MODE == 0) ? IS : (MODE == 2 ? IM : HD);
    constexpr int NTIL = DUAL ? 3 : 2;
    constexpr int NKT  = KTOT / 32;

    const int tid = threadIdx.x;
    int bx, by, bz;
    xcd_swizzle(bx, by, bz);
    const int ex  = bz;
    const int n_e = EXPERT ? counts[ex]  : T_TOK;
    const int off = EXPERT ? offsets[ex] : 0;
    const int m0  = by * 128;
    if (m0 >= n_e) return;
    const int n0 = bx * 128;

    const size_t ewoff = EXPERT ? (size_t)ex * KTOT * NTOT : 0;

    // [buf(3)][tile(NTIL)][4096 u16]; tile image = [chunk(4)][row(128)][8 u16]
    __shared__ __align__(16) u16 sh[3 * NTIL * 4096];

    const int w = tid >> 6, lane = tid & 63;
    const int lr = lane & 15, quad = lane >> 4;
    const int wm = (w >> 1) * 64, wn = (w & 1) * 64;
    const int ldsw = w * 512;            // wave-uniform dest: 64 lanes * 8 u16

    // per-thread A source for the two 4KB staging sweeps
    const u16* asrc[2];
    #pragma unroll
    for (int s = 0; s < 2; ++s) {
        int i = s * 256 + tid;
        int c = i >> 7, r = i & 127;
        int grow = m0 + r;
        int gc = grow < n_e ? grow : n_e - 1;
        size_t rowidx;
        if (MODE == 0 || MODE == 1) rowidx = (size_t)grow;
        else if (MODE == 2) rowidx = (size_t)token_list[off + gc];
        else rowidx = (size_t)(off + gc);
        asrc[s] = Asrc + rowidx * KTOT + c * 8;
    }
    const u16* b0 = B0p + ewoff + ((size_t)(n0 >> 7) * NKT) * 4096 + (size_t)tid * 8;
    const u16* b1 = nullptr;
    if constexpr (DUAL) b1 = B1p + ewoff + ((size_t)(n0 >> 7) * NKT) * 4096 + (size_t)tid * 8;

    auto stage = [&](int buf, int kt) {
        u16* A  = sh + (size_t)(buf * NTIL + 0) * 4096;
        u16* Bt = sh + (size_t)(buf * NTIL + 1) * 4096;
        #pragma unroll
        for (int s = 0; s < 2; ++s) {
            gld16(asrc[s] + kt, A + s * 2048 + ldsw);
            gld16(b0 + (size_t)(kt >> 5) * 4096 + s * 2048, Bt + s * 2048 + ldsw);
        }
        if constexpr (DUAL) {
            u16* Bu = sh + (size_t)(buf * NTIL + 2) * 4096;
            #pragma unroll
            for (int s = 0; s < 2; ++s)
                gld16(b1 + (size_t)(kt >> 5) * 4096 + s * 2048, Bu + s * 2048 + ldsw);
        }
    };

    f32x4 acc0[4][4], acc1[4][4];
    #pragma unroll
    for (int a = 0; a < 4; ++a)
        #pragma unroll
        for (int b = 0; b < 4; ++b)
            #pragma unroll
            for (int q = 0; q < 4; ++q) { acc0[a][b][q] = 0.f; if constexpr (DUAL) acc1[a][b][q] = 0.f; }

    // prologue: two tile-sets in flight; wait until buf0 landed (<= 1 set out)
    stage(0, 0);
    stage(1, 32);
    if constexpr (DUAL) asm volatile("s_waitcnt vmcnt(6)" ::: "memory");
    else                asm volatile("s_waitcnt vmcnt(4)" ::: "memory");
    __builtin_amdgcn_s_barrier();
    __builtin_amdgcn_sched_barrier(0);

    int cur = 0;
    for (int kt = 0; kt < KTOT; kt += 32) {
        // issue stage for tile k+2 into the buffer read two iterations ago
        const bool issued = (kt + 64 < KTOT);
        if (issued) stage(cur == 0 ? 2 : cur - 1, kt + 64);

        const u16* A  = sh + (size_t)(cur * NTIL + 0) * 4096;
        const u16* B0 = sh + (size_t)(cur * NTIL + 1) * 4096;

        bf16x8 af[4], bf0[4], bf1[4];
        #pragma unroll
        for (int mt = 0; mt < 4; ++mt)
            af[mt]  = *(const bf16x8*)&A [quad * 1024 + (wm + mt * 16 + lr) * 8];
        #pragma unroll
        for (int nt = 0; nt < 4; ++nt)
            bf0[nt] = *(const bf16x8*)&B0[quad * 1024 + (wn + nt * 16 + lr) * 8];
        if constexpr (DUAL) {
            const u16* B1 = sh + (size_t)(cur * NTIL + 2) * 4096;
            #pragma unroll
            for (int nt = 0; nt < 4; ++nt)
                bf1[nt] = *(const bf16x8*)&B1[quad * 1024 + (wn + nt * 16 + lr) * 8];
        }
        __builtin_amdgcn_s_setprio(1);
        #pragma unroll
        for (int mt = 0; mt < 4; ++mt)
            #pragma unroll
            for (int nt = 0; nt < 4; ++nt) {
                acc0[mt][nt] = __builtin_amdgcn_mfma_f32_16x16x32_bf16(af[mt], bf0[nt], acc0[mt][nt], 0, 0, 0);
                if constexpr (DUAL)
                    acc1[mt][nt] = __builtin_amdgcn_mfma_f32_16x16x32_bf16(af[mt], bf1[nt], acc1[mt][nt], 0, 0, 0);
            }
        __builtin_amdgcn_s_setprio(0);

        if (kt + 32 < KTOT) {
            // counted wait: <= one tile-set outstanding -> next buffer's
            // (older) loads have landed. Tail (no stage issued this iter):
            // the counted wait would pass vacuously -> drain with vmcnt(0).
            if (issued) {
                if constexpr (DUAL) asm volatile("s_waitcnt vmcnt(6)" ::: "memory");
                else                asm volatile("s_waitcnt vmcnt(4)" ::: "memory");
            } else {
                asm volatile("s_waitcnt vmcnt(0)" ::: "memory");
            }
            __builtin_amdgcn_s_barrier();
            __builtin_amdgcn_sched_barrier(0);
        }
        cur = (cur == 2) ? 0 : cur + 1;
    }

    // Epilogue. C/D layout: col = lane&15, row = quad*4 + reg (m89/m91-verified)
    if (MODE == 0 || MODE == 2) {
        #pragma unroll
        for (int mt = 0; mt < 4; ++mt)
            #pragma unroll
            for (int rg = 0; rg < 4; ++rg) {
                const int grow = m0 + wm + mt * 16 + quad * 4 + rg;
                if (!EXPERT || grow < n_e) {
                    u16* orow = outb + (size_t)(EXPERT ? (off + grow) : grow) * NTOT + n0 + wn + lr;
                    #pragma unroll
                    for (int nt = 0; nt < 4; ++nt) {
                        float g = acc0[mt][nt][rg];
                        float u = acc1[mt][nt][rg];
                        float sgm = 1.f / (1.f + __expf(-g));
                        orow[nt * 16] = f2b(g * sgm * u);
                    }
                }
            }
    } else if (MODE == 1) {
        #pragma unroll
        for (int mt = 0; mt < 4; ++mt)
            #pragma unroll
            for (int rg = 0; rg < 4; ++rg) {
                const int grow = m0 + wm + mt * 16 + quad * 4 + rg;
                const float s = scale[grow];
                float* orow = outf + (size_t)grow * HD + n0 + wn + lr;
                #pragma unroll
                for (int nt = 0; nt < 4; ++nt) orow[nt * 16] = s * acc0[mt][nt][rg];
            }
    } else {
        #pragma unroll
        for (int mt = 0; mt < 4; ++mt)
            #pragma unroll
            for (int rg = 0; rg < 4; ++rg) {
                const int grow = m0 + wm + mt * 16 + quad * 4 + rg;
                if (grow < n_e) {
                    const int tok   = token_list[off + grow];
                    const float wgt = scale[off + grow];
                    float* orow = outf + (size_t)tok * HD + n0 + wn + lr;
                    #pragma unroll
                    for (int nt = 0; nt < 4; ++nt)
                        unsafeAtomicAdd(&orow[nt * 16], wgt * acc0[mt][nt][rg]);
                }
            }
    }
}

// ---------------------------------------------------------------------------
// Legacy GEMM — fallback when ws_size is too small for the bf16 panels.
// ---------------------------------------------------------------------------
template<int MODE>
__global__ __launch_bounds__(256, 2) void gemm_l(
    const u16* __restrict__ Asrc, const float* __restrict__ B0g,
    const float* __restrict__ B1g, u16* __restrict__ outb,
    float* __restrict__ outf, const float* __restrict__ scale,
    const int* __restrict__ token_list, const int* __restrict__ counts,
    const int* __restrict__ offsets)
{
    constexpr bool DUAL   = (MODE == 0 || MODE == 2);
    constexpr bool EXPERT = (MODE >= 2);
    constexpr int KTOT = (MODE == 0 || MODE == 2) ? HD : (MODE == 1 ? IS : IM);
    constexpr int NTOT = (MODE == 0) ? IS : (MODE == 2 ? IM : HD);
    constexpr int LDA  = (MODE == 0 || MODE == 2) ? HD : (MODE == 1 ? IS : IM);

    const int tid = threadIdx.x;
    const int ex  = blockIdx.z;
    const int n_e = EXPERT ? counts[ex]  : T_TOK;
    const int off = EXPERT ? offsets[ex] : 0;
    const int m0  = blockIdx.y * 128;
    if (m0 >= n_e) return;
    const int n0 = blockIdx.x * 128;

    const float* B0 = B0g + (EXPERT ? (size_t)ex * KTOT * NTOT : 0);
    const float* B1 = DUAL ? (B1g + (EXPERT ? (size_t)ex * KTOT * NTOT : 0)) : nullptr;

    __shared__ __align__(16) u16 As [128 * 40];
    __shared__ __align__(16) u16 Bs0[128 * 40];
    __shared__ __align__(16) u16 Bs1[DUAL ? 128 * 40 : 8];

    const u16* aptr[2]; int aoff[2];
    #pragma unroll
    for (int i = 0; i < 2; ++i) {
        int c = tid + i * 256;
        int r = c >> 2, xo = c & 3;
        int grow = m0 + r;
        size_t rowidx;
        if (MODE == 0 || MODE == 1) rowidx = (size_t)grow;
        else if (MODE == 2) rowidx = (size_t)((grow < n_e) ? token_list[off + grow] : 0);
        else rowidx = (size_t)(off + grow);
        aptr[i] = Asrc + rowidx * LDA + xo * 8;
        aoff[i] = r * 40 + xo * 8;
    }

    const int kb = tid >> 5, nb = tid & 31;
    const float* bp0 = B0 + (size_t)(kb * 4) * NTOT + n0 + nb * 4;
    const float* bp1 = DUAL ? (B1 + (size_t)(kb * 4) * NTOT + n0 + nb * 4) : nullptr;
    const int bo = (nb * 4) * 40 + kb * 4;

    const int lane = tid & 63, wv = tid >> 6;
    const int wm = (wv >> 1) * 64, wn = (wv & 1) * 64;
    const int lr = lane & 15, quad = lane >> 4;

    f32x4 acc0[4][4], acc1[4][4];
    #pragma unroll
    for (int a = 0; a < 4; ++a)
        #pragma unroll
        for (int b = 0; b < 4; ++b)
            #pragma unroll
            for (int q = 0; q < 4; ++q) { acc0[a][b][q] = 0.f; if (DUAL) acc1[a][b][q] = 0.f; }

    for (int kt = 0; kt < KTOT; kt += 32) {
        uint4 av0 = *(const uint4*)(aptr[0] + kt);
        uint4 av1 = *(const uint4*)(aptr[1] + kt);
        float4 b0v[4], b1v[4];
        #pragma unroll
        for (int i = 0; i < 4; ++i) b0v[i] = *(const float4*)(bp0 + (size_t)(kt + i) * NTOT);
        if (DUAL) {
            #pragma unroll
            for (int i = 0; i < 4; ++i) b1v[i] = *(const float4*)(bp1 + (size_t)(kt + i) * NTOT);
        }
        __syncthreads();
        *(uint4*)&As[aoff[0]] = av0;
        *(uint4*)&As[aoff[1]] = av1;
        {
            const float* f0 = (const float*)b0v;
            #pragma unroll
            for (int j = 0; j < 4; ++j) {
                ushort4 tw; tw.x = f2b(f0[0 * 4 + j]); tw.y = f2b(f0[1 * 4 + j]);
                            tw.z = f2b(f0[2 * 4 + j]); tw.w = f2b(f0[3 * 4 + j]);
                *(ushort4*)&Bs0[bo + j * 40] = tw;
            }
        }
        if (DUAL) {
            const float* f1 = (const float*)b1v;
            #pragma unroll
            for (int j = 0; j < 4; ++j) {
                ushort4 tw; tw.x = f2b(f1[0 * 4 + j]); tw.y = f2b(f1[1 * 4 + j]);
                            tw.z = f2b(f1[2 * 4 + j]); tw.w = f2b(f1[3 * 4 + j]);
                *(ushort4*)&Bs1[bo + j * 40] = tw;
            }
        }
        __syncthreads();

        bf16x8 af[4], bf0[4], bf1[4];
        #pragma unroll
        for (int mt = 0; mt < 4; ++mt) af[mt]  = *(const bf16x8*)&As [(wm + mt * 16 + lr) * 40 + quad * 8];
        #pragma unroll
        for (int nt = 0; nt < 4; ++nt) bf0[nt] = *(const bf16x8*)&Bs0[(wn + nt * 16 + lr) * 40 + quad * 8];
        if (DUAL) {
            #pragma unroll
            for (int nt = 0; nt < 4; ++nt) bf1[nt] = *(const bf16x8*)&Bs1[(wn + nt * 16 + lr) * 40 + quad * 8];
        }
        #pragma unroll
        for (int mt = 0; mt < 4; ++mt)
            #pragma unroll
            for (int nt = 0; nt < 4; ++nt) {
                acc0[mt][nt] = __builtin_amdgcn_mfma_f32_16x16x32_bf16(af[mt], bf0[nt], acc0[mt][nt], 0, 0, 0);
                if (DUAL)
                    acc1[mt][nt] = __builtin_amdgcn_mfma_f32_16x16x32_bf16(af[mt], bf1[nt], acc1[mt][nt], 0, 0, 0);
            }
    }

    if (MODE == 0 || MODE == 2) {
        #pragma unroll
        for (int mt = 0; mt < 4; ++mt)
            #pragma unroll
            for (int rg = 0; rg < 4; ++rg) {
                const int grow = m0 + wm + mt * 16 + quad * 4 + rg;
                if (!EXPERT || grow < n_e) {
                    u16* orow = outb + (size_t)(EXPERT ? (off + grow) : grow) * NTOT + n0 + wn + lr;
                    #pragma unroll
                    for (int nt = 0; nt < 4; ++nt) {
                        float g = acc0[mt][nt][rg];
                        float u = acc1[mt][nt][rg];
                        float sgm = 1.f / (1.f + __expf(-g));
                        orow[nt * 16] = f2b(g * sgm * u);
                    }
                }
            }
    } else if (MODE == 1) {
        #pragma unroll
        for (int mt = 0; mt < 4; ++mt)
            #pragma unroll
            for (int rg = 0; rg < 4; ++rg) {
                const int grow = m0 + wm + mt * 16 + quad * 4 + rg;
                const float s = scale[grow];
                float* orow = outf + (size_t)grow * HD + n0 + wn + lr;
                #pragma unroll
                for (int nt = 0; nt < 4; ++nt) orow[nt * 16] = s * acc0[mt][nt][rg];
            }
    } else {
        #pragma unroll
        for (int mt = 0; mt < 4; ++mt)
            #pragma unroll
            for (int rg = 0; rg < 4; ++rg) {
                const int grow = m0 + wm + mt * 16 + quad * 4 + rg;
                if (grow < n_e) {
                    const int tok   = token_list[off + grow];
                    const float wgt = scale[off + grow];
                    float* orow = outf + (size_t)tok * HD + n0 + wn + lr;
                    #pragma unroll
                    for (int nt = 0; nt < 4; ++nt)
                        unsafeAtomicAdd(&orow[nt * 16], wgt * acc0[mt][nt][rg]);
                }
            }
    }
}

// ---------------------------------------------------------------------------
// workspace layout (bytes)
// ---------------------------------------------------------------------------
#define OFF_XB      ((size_t)0)            // T*H bf16            = 33554432
#define OFF_HSH     ((size_t)33554432)     // T*IS bf16           = 67108864
#define OFF_HMID    ((size_t)100663296)    // T*K*IM bf16         = 100663296
#define OFF_SG      ((size_t)201326592)    // T fp32
#define OFF_TOPKI   ((size_t)201359360)
#define OFF_TOPKW   ((size_t)201621504)
#define OFF_TOKL    ((size_t)201883648)
#define OFF_WGTL    ((size_t)202145792)
#define OFF_COUNTS  ((size_t)202407936)
#define OFF_CURSOR  ((size_t)202408064)
#define OFF_OFFSETS ((size_t)202408192)
// bf16 weight panels (fast path only)
#define OFF_PWG     ((size_t)202408448)    // 32*2048*768*2  = 100663296
#define OFF_PWU     ((size_t)303071744)
#define OFF_PWD     ((size_t)403735040)
#define OFF_PSG     ((size_t)504398336)    // 2048*4096*2    = 16777216
#define OFF_PSU     ((size_t)521175552)
#define OFF_PSD     ((size_t)537952768)
#define WS_NEED     ((size_t)554729984)

extern "C" void kernel_launch(void* const* d_in, const int* in_sizes, int n_in,
                              void* d_out, int out_size, void* d_ws, size_t ws_size,
                              hipStream_t stream)
{
    const float* x   = (const float*)d_in[0];
    const float* gw  = (const float*)d_in[1];
    const float* Wg  = (const float*)d_in[2];
    const float* Wu  = (const float*)d_in[3];
    const float* Wd  = (const float*)d_in[4];
    const float* Sg  = (const float*)d_in[5];
    const float* Su  = (const float*)d_in[6];
    const float* Sd  = (const float*)d_in[7];
    const float* sgw = (const float*)d_in[8];

    float* out        = (float*)d_out;
    float* logits_out = out + (size_t)T_TOK * HD;

    char* ws = (char*)d_ws;
    u16*   xb      = (u16*)  (ws + OFF_XB);
    u16*   hshared = (u16*)  (ws + OFF_HSH);
    u16*   hmid    = (u16*)  (ws + OFF_HMID);
    float* sgvals  = (float*)(ws + OFF_SG);
    int*   topk_i  = (int*)  (ws + OFF_TOPKI);
    float* topk_wv = (float*)(ws + OFF_TOPKW);
    int*   tok_lst = (int*)  (ws + OFF_TOKL);
    float* wgt_lst = (float*)(ws + OFF_WGTL);
    int*   counts  = (int*)  (ws + OFF_COUNTS);
    int*   cursor  = (int*)  (ws + OFF_CURSOR);
    int*   offsets = (int*)  (ws + OFF_OFFSETS);

    hipMemsetAsync(counts, 0, 256, stream);  // counts + cursor

    router_kernel<<<T_TOK, 256, 0, stream>>>(x, gw, sgw, logits_out, xb, sgvals,
                                             topk_i, topk_wv, counts);
    offsets_kernel<<<1, 64, 0, stream>>>(counts, offsets, cursor);
    scatter_kernel<<<T_TOK * KTOP / 256, 256, 0, stream>>>(topk_i, topk_wv, cursor,
                                                           tok_lst, wgt_lst);

    if (ws_size >= WS_NEED) {
        u16* pWg = (u16*)(ws + OFF_PWG);
        u16* pWu = (u16*)(ws + OFF_PWU);
        u16* pWd = (u16*)(ws + OFF_PWD);
        u16* pSg = (u16*)(ws + OFF_PSG);
        u16* pSu = (u16*)(ws + OFF_PSU);
        u16* pSd = (u16*)(ws + OFF_PSD);

        convert_k<<<dim3(IM / 128, HD / 32, NE), 256, 0, stream>>>(Wg, pWg, HD, IM);
        convert_k<<<dim3(IM / 128, HD / 32, NE), 256, 0, stream>>>(Wu, pWu, HD, IM);
        convert_k<<<dim3(HD / 128, IM / 32, NE), 256, 0, stream>>>(Wd, pWd, IM, HD);
        convert_k<<<dim3(IS / 128, HD / 32, 1),  256, 0, stream>>>(Sg, pSg, HD, IS);
        convert_k<<<dim3(IS / 128, HD / 32, 1),  256, 0, stream>>>(Su, pSu, HD, IS);
        convert_k<<<dim3(HD / 128, IS / 32, 1),  256, 0, stream>>>(Sd, pSd, IS, HD);

        gemm_f<0><<<dim3(IS / 128, T_TOK / 128, 1), 256, 0, stream>>>(
            xb, pSg, pSu, hshared, nullptr, nullptr, nullptr, nullptr, nullptr);
        gemm_f<2><<<dim3(IM / 128, T_TOK / 128, NE), 256, 0, stream>>>(
            xb, pWg, pWu, hmid, nullptr, nullptr, tok_lst, counts, offsets);
        gemm_f<1><<<dim3(HD / 128, T_TOK / 128, 1), 256, 0, stream>>>(
            hshared, pSd, nullptr, nullptr, out, sgvals, nullptr, nullptr, nullptr);
        gemm_f<3><<<dim3(HD / 128, T_TOK / 128, NE), 256, 0, stream>>>(
            hmid, pWd, nullptr, nullptr, out, wgt_lst, tok_lst, counts, offsets);
    } else {
        gemm_l<0><<<dim3(IS / 128, T_TOK / 128, 1), 256, 0, stream>>>(
            xb, Sg, Su, hshared, nullptr, nullptr, nullptr, nullptr, nullptr);
        gemm_l<2><<<dim3(IM / 128, T_TOK / 128, NE), 256, 0, stream>>>(
            xb, Wg, Wu, hmid, nullptr, nullptr, tok_lst, counts, offsets);
        gemm_l<1><<<dim3(HD / 128, T_TOK / 128, 1), 256, 0, stream>>>(
            hshared, Sd, nullptr, nullptr, out, sgvals, nullptr, nullptr, nullptr);
        gemm_l<3><<<dim3(HD / 128, T_TOK / 128, NE), 256, 0, stream>>>(
            hmid, Wd, nullptr, nullptr, out, wgt_lst, tok_lst, counts, offsets);
    }
}